// Round 6
// baseline (248.088 us; speedup 1.0000x reference)
//
#include <hip/hip_runtime.h>
#include <stdint.h>

// CausalSelfAttention, B=4 N=2048 D=1024, softmax over QUERY axis (axis=1).
// Pipeline: cast->bf16 | QKV gemm (256x128 BK=32 2-buf, 2 blocks/CU) | V transpose
//           | S=QK^T/32 (same kernel, causal tile skip, bf16)
//           | column stats (ILP 8-col/thread) | P=exp(s-M)*rZ (PV-read set, 128-tile)
//           | O = P @ V (128^2 gemm_bt, kEnd=bm0+128, ~7 blocks/CU).

#define BM 128
#define BN 128
#define BK 32

#define QCH 32
#define NQC 64   // N / QCH

typedef __attribute__((ext_vector_type(8))) short short8;   // 8 bf16 = 4 VGPR
typedef __attribute__((ext_vector_type(4))) float f32x4;

static __device__ __forceinline__ ushort f2bf(float f) {
  union { float f; uint32_t u; } v; v.f = f;
  uint32_t r = v.u + 0x7FFFu + ((v.u >> 16) & 1u);   // RNE
  return (ushort)(r >> 16);
}
static __device__ __forceinline__ float bf2f(ushort u) {
  union { uint32_t u; float f; } v; v.u = ((uint32_t)u) << 16;
  return v.f;
}

static __device__ __forceinline__ void gload_lds16(const ushort* g, ushort* l) {
  __builtin_amdgcn_global_load_lds(
      (const __attribute__((address_space(1))) void*)g,
      (__attribute__((address_space(3))) void*)l, 16, 0, 0);
}

#define SBAR()   __builtin_amdgcn_s_barrier()
#define SCHED0() __builtin_amdgcn_sched_barrier(0)
#define WAITL0() do { asm volatile("s_waitcnt lgkmcnt(0)" ::: "memory"); SCHED0(); } while (0)
#define WAITV0() asm volatile("s_waitcnt vmcnt(0)" ::: "memory")

// ---------------- casts ----------------
__global__ void cast_f32_bf16(const float* __restrict__ in, ushort* __restrict__ out, int n4) {
  int i = blockIdx.x * blockDim.x + threadIdx.x;
  if (i >= n4) return;
  float4 v = ((const float4*)in)[i];
  ushort4 o;
  o.x = f2bf(v.x); o.y = f2bf(v.y); o.z = f2bf(v.z); o.w = f2bf(v.w);
  ((ushort4*)out)[i] = o;
}

// =====================================================================
// 256(M) x 128(N) / BK=32 / 8-wave / DOUBLE-buffer LDS (2 x 24KB = 48KB)
// -> 2 blocks/CU (16 waves/CU) so cross-block wave overlap hides the
// barrier+stage serialization (m114).  STAGE(t+1) issues at loop top:
// full-iteration flight before the end-of-iter vmcnt(0)+barrier.
// C = alpha * A @ Bt^T.  A:[M][K], Bt:[Nn][K], K%32==0.
// CMODE: 0 = bf16 C, 1 = f32 C.
// KMODE: 0 = full K; 1 = kEnd=min(K,bm0+256);
//        2 = skip blocks with bn0 >= bm0+256 (causal S), full K.
// Swizzle (R2-verified, 0 conflicts): 16B-chunk c of row stored at
// c ^ ((row>>1)&3); applied on pre-swizzled global source AND ds_read addr.
// Waves: wr=wave>>1 (4 x 64 rows), wc=wave&1 (2 x 64 cols); acc 4x4.
// =====================================================================
template <int CMODE, int KMODE>
__global__ __launch_bounds__(512, 4) void gemm256c(
    const ushort* __restrict__ A, const ushort* __restrict__ Bt, void* __restrict__ C,
    int M, int Nn, int K, long sA, long sB, long sC, float alpha)
{
  const int bm0 = blockIdx.x * 256;
  const int bn0 = blockIdx.y * 128;
  if (KMODE == 2 && bn0 >= bm0 + 256) return;

  const ushort* Ab = A + (long)blockIdx.z * sA;
  const ushort* Bb = Bt + (long)blockIdx.z * sB;

  int kEnd = K;
  if (KMODE == 1) { int ke = bm0 + 256; kEnd = ke < K ? ke : K; }
  const int nk = kEnd >> 5;          // K-tiles of 32

  // per buffer: A[256][32]bf16 = 16KB @ 0, B[128][32]bf16 = 8KB @ 16384
  __shared__ uint4 lds_v[49152 / 16];
  char* lds = (char*)lds_v;

  const int tid  = threadIdx.x;
  const int lane = tid & 63;
  const int wave = tid >> 6;
  const int wr   = wave >> 1;        // 0..3 -> rows wr*64
  const int wc   = wave & 1;         // 0..1 -> cols wc*64
  const int fr   = lane & 15;
  const int fg   = lane >> 4;        // 16B chunk (8 bf16 of k)

  f32x4 acc[4][4];
#pragma unroll
  for (int i = 0; i < 4; ++i)
#pragma unroll
    for (int j = 0; j < 4; ++j) acc[i][j] = (f32x4){0.f, 0.f, 0.f, 0.f};

  // stage tile tt into buf tt&1: A 2 segs/thread, B 1 seg/thread (3 loads)
  auto STAGE = [&](int tt) {
    if (tt >= nk) return;
    char* slab = lds + (tt & 1) * 24576;
#pragma unroll
    for (int u = 0; u < 2; ++u) {
      int s = u * 512 + tid;
      int row = s >> 2;                       // 0..255
      int cc = (s & 3) ^ ((row >> 1) & 3);    // pre-swizzled source chunk
      gload_lds16(Ab + (long)(bm0 + row) * K + tt * 32 + cc * 8,
                  (ushort*)(slab + s * 16));
    }
    {
      int s = tid;
      int row = s >> 2;                       // 0..127
      int cc = (s & 3) ^ ((row >> 1) & 3);
      gload_lds16(Bb + (long)(bn0 + row) * K + tt * 32 + cc * 8,
                  (ushort*)(slab + 16384 + s * 16));
    }
  };

  // prologue
  STAGE(0);
  WAITV0();
  SBAR();

  for (int t = 0; t < nk; ++t) {
    char* slab = lds + (t & 1) * 24576;
    STAGE(t + 1);                    // into other buf; flight = whole iteration

    short8 a[4], b[4];
#pragma unroll
    for (int i = 0; i < 4; ++i) {
      int row = wr * 64 + i * 16 + fr;
      int cc = fg ^ ((row >> 1) & 3);
      a[i] = *(const short8*)(slab + row * 64 + cc * 16);
    }
#pragma unroll
    for (int j = 0; j < 4; ++j) {
      int row = wc * 64 + j * 16 + fr;
      int cc = fg ^ ((row >> 1) & 3);
      b[j] = *(const short8*)(slab + 16384 + row * 64 + cc * 16);
    }
    WAITL0();
    __builtin_amdgcn_s_setprio(1);
#pragma unroll
    for (int i = 0; i < 4; ++i)
#pragma unroll
      for (int j = 0; j < 4; ++j)
        acc[i][j] = __builtin_amdgcn_mfma_f32_16x16x32_bf16(a[i], b[j], acc[i][j], 0, 0, 0);
    __builtin_amdgcn_s_setprio(0);

    WAITV0();                        // t+1's 3 loads (had full iter to land)
    SBAR();                          // all waves' loads visible; buf swap safe
  }

  // epilogue: C/D map: col = lane&15, row = (lane>>4)*4 + r
  if (CMODE == 0) {
    ushort* Cb = (ushort*)C + (long)blockIdx.z * sC;
#pragma unroll
    for (int i = 0; i < 4; ++i)
#pragma unroll
      for (int j = 0; j < 4; ++j)
#pragma unroll
        for (int r = 0; r < 4; ++r) {
          int row = bm0 + wr * 64 + i * 16 + fg * 4 + r;
          int col = bn0 + wc * 64 + j * 16 + fr;
          Cb[(long)row * Nn + col] = f2bf(acc[i][j][r] * alpha);
        }
  } else {
    float* Cb = (float*)C + (long)blockIdx.z * sC;
#pragma unroll
    for (int i = 0; i < 4; ++i)
#pragma unroll
      for (int j = 0; j < 4; ++j)
#pragma unroll
        for (int r = 0; r < 4; ++r) {
          int row = bm0 + wr * 64 + i * 16 + fg * 4 + r;
          int col = bn0 + wc * 64 + j * 16 + fr;
          Cb[(long)row * Nn + col] = acc[i][j][r] * alpha;
        }
  }
}

// ---------------- 128^2 bf16 GEMM (PV with causal k-limit; ~7 blocks/CU) ----------------
template <int CMODE, int KMODE>
__global__ __launch_bounds__(256) void gemm_bt(
    const ushort* __restrict__ A, const ushort* __restrict__ Bt, void* __restrict__ C,
    int M, int Nn, int K, long sA, long sB, long sC, float alpha)
{
  const int bm0 = blockIdx.x * BM;
  const int bn0 = blockIdx.y * BN;
  if (KMODE == 2 && bn0 > bm0) return;

  const ushort* Ab = A + (long)blockIdx.z * sA;
  const ushort* Bb = Bt + (long)blockIdx.z * sB;

  int kEnd = K;
  if (KMODE == 1) { int ke = bm0 + BM; kEnd = ke < K ? ke : K; }

  __shared__ ushort As[BM * BK];
  __shared__ ushort Bs[BN * BK];

  const int tid  = threadIdx.x;
  const int lane = tid & 63;
  const int wave = tid >> 6;
  const int wm   = (wave >> 1) * 64;
  const int wn   = (wave & 1) * 64;
  const int fr   = lane & 15;
  const int fg   = lane >> 4;

  f32x4 acc[4][4];
#pragma unroll
  for (int i = 0; i < 4; ++i)
#pragma unroll
    for (int j = 0; j < 4; ++j) acc[i][j] = (f32x4){0.f, 0.f, 0.f, 0.f};

  for (int k0 = 0; k0 < kEnd; k0 += BK) {
#pragma unroll
    for (int it = 0; it < 2; ++it) {
      int s = it * 256 + tid;
      int row = s >> 2;
      int col = (s & 3) * 8;
      gload_lds16(Ab + (long)(bm0 + row) * K + (k0 + col), &As[s * 8]);
      gload_lds16(Bb + (long)(bn0 + row) * K + (k0 + col), &Bs[s * 8]);
    }
    __syncthreads();

    short8 af[4], bfg[4];
#pragma unroll
    for (int i = 0; i < 4; ++i)
      af[i] = *(const short8*)&As[(wm + i * 16 + fr) * BK + fg * 8];
#pragma unroll
    for (int j = 0; j < 4; ++j)
      bfg[j] = *(const short8*)&Bs[(wn + j * 16 + fr) * BK + fg * 8];
#pragma unroll
    for (int i = 0; i < 4; ++i)
#pragma unroll
      for (int j = 0; j < 4; ++j)
        acc[i][j] = __builtin_amdgcn_mfma_f32_16x16x32_bf16(af[i], bfg[j], acc[i][j], 0, 0, 0);
    __syncthreads();
  }

  if (CMODE == 0) {
    ushort* Cb = (ushort*)C + (long)blockIdx.z * sC;
#pragma unroll
    for (int i = 0; i < 4; ++i)
#pragma unroll
      for (int j = 0; j < 4; ++j)
#pragma unroll
        for (int r = 0; r < 4; ++r) {
          int row = bm0 + wm + i * 16 + fg * 4 + r;
          int col = bn0 + wn + j * 16 + fr;
          Cb[(long)row * Nn + col] = f2bf(acc[i][j][r] * alpha);
        }
  } else {
    float* Cb = (float*)C + (long)blockIdx.z * sC;
#pragma unroll
    for (int i = 0; i < 4; ++i)
#pragma unroll
      for (int j = 0; j < 4; ++j)
#pragma unroll
        for (int r = 0; r < 4; ++r) {
          int row = bm0 + wm + i * 16 + fg * 4 + r;
          int col = bn0 + wn + j * 16 + fr;
          Cb[(long)row * Nn + col] = acc[i][j][r] * alpha;
        }
  }
}

// ---------------- bf16 transpose ----------------
__global__ void transpose_bf16(const ushort* __restrict__ in, ushort* __restrict__ out,
                               int rows, int cols) {
  __shared__ ushort t[64][65];
  int c0 = blockIdx.x * 64, r0 = blockIdx.y * 64;
  long base = (long)blockIdx.z * rows * cols;
  int tid = threadIdx.x;
#pragma unroll
  for (int i = 0; i < 16; ++i) {
    int idx = i * 256 + tid, r = idx >> 6, c = idx & 63;
    t[r][c] = in[base + (long)(r0 + r) * cols + c0 + c];
  }
  __syncthreads();
#pragma unroll
  for (int i = 0; i < 16; ++i) {
    int idx = i * 256 + tid, r = idx >> 6, c = idx & 63;
    out[base + (long)(c0 + r) * rows + r0 + c] = t[c][r];
  }
}

// ---------------- column softmax stats over q axis (8 cols/thread, 2-pass) ----------------
// grid (Nq/512, Nq/QCH, B), block 64 threads.  Partials: pM/pZ [b][NQC][Nq].
__global__ void colstats_partial(const ushort* __restrict__ S, float* __restrict__ pM,
                                 float* __restrict__ pZ, int Nq) {
  const int k0 = (blockIdx.x * 64 + threadIdx.x) * 8;
  const int qc = blockIdx.y;
  const int b  = blockIdx.z;
  const int q0 = qc * QCH, q1 = q0 + QCH;
  const long o = ((long)(b * NQC + qc)) * Nq + k0;

  float m[8], z[8];
#pragma unroll
  for (int j = 0; j < 8; ++j) { m[j] = -3.0e38f; z[j] = 0.f; }

  const int qs = q0 > k0 ? q0 : k0;          // causal: only q >= k valid
  if (qs < q1) {
    const ushort* Sb = S + (long)b * Nq * Nq;
    for (int q = qs; q < q1; ++q) {
      union { uint4 v; ushort u[8]; } d;
      d.v = *(const uint4*)(Sb + (long)q * Nq + k0);
#pragma unroll
      for (int j = 0; j < 8; ++j) {
        float s = bf2f(d.u[j]);
        m[j] = (q >= k0 + j) ? fmaxf(m[j], s) : m[j];
      }
    }
    for (int q = qs; q < q1; ++q) {
      union { uint4 v; ushort u[8]; } d;
      d.v = *(const uint4*)(Sb + (long)q * Nq + k0);
#pragma unroll
      for (int j = 0; j < 8; ++j) {
        float e = __expf(bf2f(d.u[j]) - m[j]);
        z[j] += (q >= k0 + j) ? e : 0.f;
      }
    }
  }
#pragma unroll
  for (int j = 0; j < 8; ++j) { pM[o + j] = m[j]; pZ[o + j] = z[j]; }
}

__global__ void colstats_combine(const float* __restrict__ pM, const float* __restrict__ pZ,
                                 float2* __restrict__ Mz, int Nq) {
  int idx = blockIdx.x * 256 + threadIdx.x;   // b*Nq + k
  int b = idx / Nq, k = idx - b * Nq;
  const float* PM = pM + (long)b * NQC * Nq + k;
  const float* PZ = pZ + (long)b * NQC * Nq + k;
  float M = -3.0e38f;
  for (int c = 0; c < NQC; ++c) M = fmaxf(M, PM[(long)c * Nq]);
  float Z = 0.f;
  for (int c = 0; c < NQC; ++c) Z += PZ[(long)c * Nq] * __expf(PM[(long)c * Nq] - M);
  Mz[idx] = make_float2(M, 1.0f / Z);
}

// ---------------- P = exp(s - M[k]) * rZ[k], over the PV READ SET, in place ------------
// PV (gemm_bt, q-tile [t*128,(t+1)*128)) reads k in [0, (t+1)*128): zero k>q up
// to the q-tile's 128 boundary; skip only groups beyond that.
__global__ void make_p(ushort* __restrict__ S, const float2* __restrict__ Mz, int Nq) {
  long t = (long)blockIdx.x * 256 + threadIdx.x;
  int kb = (int)(t % (Nq / 8)) * 8;
  long row = t / (Nq / 8);
  int q = (int)(row % Nq);
  int b = (int)(row / Nq);
  int kend = ((q >> 7) + 1) << 7;    // PV k-limit for this row's 128-tile
  if (kb >= kend) return;            // never read downstream
  ushort* Sp = S + row * Nq + kb;
  union { uint4 v; ushort u[8]; } d, o;
  d.v = *(const uint4*)Sp;
  const float2* mz = Mz + (long)b * Nq + kb;
#pragma unroll
  for (int j = 0; j < 8; ++j) {
    float2 m = mz[j];
    float p = (q >= kb + j) ? __expf(bf2f(d.u[j]) - m.x) * m.y : 0.f;
    o.u[j] = f2bf(p);
  }
  *(uint4*)Sp = o.v;
}

// ---------------- launch ----------------
extern "C" void kernel_launch(void* const* d_in, const int* in_sizes, int n_in,
                              void* d_out, int out_size, void* d_ws, size_t ws_size,
                              hipStream_t stream) {
  const float* x  = (const float*)d_in[0];
  const float* Wq = (const float*)d_in[1];
  const float* Wk = (const float*)d_in[2];
  const float* Wv = (const float*)d_in[3];
  float* out = (float*)d_out;

  const int B = 4, N = 2048, D = 1024;
  const long BND = (long)B * N * D;

  char* ws = (char*)d_ws;
  ushort* xb  = (ushort*)ws;                         // [B*N][D] bf16, 16MB
  ushort* Vt  = xb;                                  // aliases xb (dead after K1)
  ushort* Wb  = xb + BND;                            // [3][D][D] bf16
  ushort* QKV = Wb + 3L * D * D;                     // [3][B*N][D]
  ushort* Qb  = QKV;
  ushort* Kb  = QKV + BND;
  ushort* Vb  = QKV + 2 * BND;
  ushort* S   = QKV + 3 * BND;                       // [B][N][N] bf16
  float*  pM  = (float*)(S + (long)B * N * N);       // [B][NQC][N] f32, 2MB
  float*  pZ  = pM + (long)B * NQC * N;              // 2MB
  float2* Mz  = (float2*)(pZ + (long)B * NQC * N);   // [B][N]

  // K0: casts
  cast_f32_bf16<<<(int)(BND / 4 / 256), 256, 0, stream>>>(x, xb, (int)(BND / 4));
  cast_f32_bf16<<<(D * D / 4) / 256, 256, 0, stream>>>(Wq, Wb, D * D / 4);
  cast_f32_bf16<<<(D * D / 4) / 256, 256, 0, stream>>>(Wk, Wb + (long)D * D, D * D / 4);
  cast_f32_bf16<<<(D * D / 4) / 256, 256, 0, stream>>>(Wv, Wb + 2L * D * D, D * D / 4);

  // K1: Q/K/V projections: 768 blocks = exactly 3/CU at 2 blocks/CU resident
  {
    dim3 g(B * N / 256, D / 128, 3);
    gemm256c<0, 0><<<g, 512, 0, stream>>>(xb, Wb, (void*)QKV, B * N, D, D,
                                          0L, (long)D * D, BND, 1.0f);
  }

  // K2: V -> V^T (xb dead now)
  {
    dim3 g(D / 64, N / 64, B);
    transpose_bf16<<<g, 256, 0, stream>>>(Vb, Vt, N, D);
  }

  // K3: S = Q K^T / 32, tiles with bn0 < bm0+256 only (288 live blocks)
  {
    dim3 g(N / 256, N / 128, B);
    gemm256c<0, 2><<<g, 512, 0, stream>>>(Qb, Kb, (void*)S, N, N, D,
                                          (long)N * D, (long)N * D, (long)N * N, 0.03125f);
  }

  // K3b: column (query-axis) softmax stats
  {
    dim3 g(N / 512, N / QCH, B);
    colstats_partial<<<g, 64, 0, stream>>>(S, pM, pZ, N);
    colstats_combine<<<(B * N) / 256, 256, 0, stream>>>(pM, pZ, Mz, N);
  }

  // K4: P in place (PV read set, 128-tile boundary)
  make_p<<<(int)((long)B * N * N / 8 / 256), 256, 0, stream>>>(S, Mz, N);

  // K5: O = P @ V (kEnd = bm0+128), 512 triangular blocks, high occupancy
  {
    dim3 g(N / BM, D / BN, B);
    gemm_bt<1, 1><<<g, 256, 0, stream>>>(S, Vt, (void*)out, N, D, N,
                                         (long)N * N, (long)D * N, (long)N * D, 1.0f);
  }
}

// Round 7
// 239.835 us; speedup vs baseline: 1.0344x; 1.0344x over previous
//
#include <hip/hip_runtime.h>
#include <stdint.h>

// CausalSelfAttention, B=4 N=2048 D=1024, softmax over QUERY axis (axis=1).
// Pipeline: cast(1 kernel) | QKV gemm (256x128 BK=32 TRIPLE-buf vmcnt(3)) |
//           V transpose | S=QK^T/32 (same kernel, causal skip, bf16) |
//           column stats (ILP 8-col/thread) | P=exp(s-M)*rZ (PV-read set) |
//           O = P @ V (128^2 gemm_bt, kEnd=bm0+128).

#define BM 128
#define BN 128
#define BK 32

#define QCH 32
#define NQC 64   // N / QCH

typedef __attribute__((ext_vector_type(8))) short short8;   // 8 bf16 = 4 VGPR
typedef __attribute__((ext_vector_type(4))) float f32x4;

static __device__ __forceinline__ ushort f2bf(float f) {
  union { float f; uint32_t u; } v; v.f = f;
  uint32_t r = v.u + 0x7FFFu + ((v.u >> 16) & 1u);   // RNE
  return (ushort)(r >> 16);
}
static __device__ __forceinline__ float bf2f(ushort u) {
  union { uint32_t u; float f; } v; v.u = ((uint32_t)u) << 16;
  return v.f;
}

static __device__ __forceinline__ void gload_lds16(const ushort* g, ushort* l) {
  __builtin_amdgcn_global_load_lds(
      (const __attribute__((address_space(1))) void*)g,
      (__attribute__((address_space(3))) void*)l, 16, 0, 0);
}

#define SBAR()   __builtin_amdgcn_s_barrier()
#define SCHED0() __builtin_amdgcn_sched_barrier(0)
#define WAITL0() do { asm volatile("s_waitcnt lgkmcnt(0)" ::: "memory"); SCHED0(); } while (0)
#define WAITV3() asm volatile("s_waitcnt vmcnt(3)" ::: "memory")
#define WAITV0() asm volatile("s_waitcnt vmcnt(0)" ::: "memory")

// ---------------- merged casts (x + Wq + Wk + Wv in one dispatch) ----------------
// region 0: n_x4 float4-groups of x -> xb; regions 1..3: n_w4 groups each -> Wb[z].
__global__ void cast_all(const float* __restrict__ x, const float* __restrict__ Wq,
                         const float* __restrict__ Wk, const float* __restrict__ Wv,
                         ushort* __restrict__ xb, ushort* __restrict__ Wb,
                         int n_x4, int n_w4) {
  int i = blockIdx.x * blockDim.x + threadIdx.x;
  const float* src; ushort* dst; int off;
  if (i < n_x4) { src = x; dst = xb; off = i; }
  else {
    int j = i - n_x4;
    int z = j / n_w4;
    off = j - z * n_w4;
    src = (z == 0) ? Wq : (z == 1) ? Wk : Wv;
    dst = Wb + (long)z * n_w4 * 4;
  }
  float4 v = ((const float4*)src)[off];
  ushort4 o;
  o.x = f2bf(v.x); o.y = f2bf(v.y); o.z = f2bf(v.z); o.w = f2bf(v.w);
  ((ushort4*)dst)[off] = o;
}

// =====================================================================
// 256(M) x 128(N) / BK=32 / 8-wave / TRIPLE-buffer LDS (3 x 24KB = 72KB)
// -> still 2 blocks/CU; STAGE(t+2) gives each staged tile ~2 iterations
// of flight; counted vmcnt(3) in the main loop (never drains to 0).
// C = alpha * A @ Bt^T.  A:[M][K], Bt:[Nn][K], K%32==0.
// CMODE: 0 = bf16 C, 1 = f32 C.
// KMODE: 0 = full K; 1 = kEnd=min(K,bm0+256);
//        2 = skip blocks with bn0 >= bm0+256 (causal S), full K.
// Swizzle (R2-verified, 0 conflicts): 16B-chunk c of row stored at
// c ^ ((row>>1)&3); applied on pre-swizzled global source AND ds_read addr.
// Waves: wr=wave>>1 (4 x 64 rows), wc=wave&1 (2 x 64 cols); acc 4x4.
// =====================================================================
template <int CMODE, int KMODE>
__global__ __launch_bounds__(512, 4) void gemm256c(
    const ushort* __restrict__ A, const ushort* __restrict__ Bt, void* __restrict__ C,
    int M, int Nn, int K, long sA, long sB, long sC, float alpha)
{
  const int bm0 = blockIdx.x * 256;
  const int bn0 = blockIdx.y * 128;
  if (KMODE == 2 && bn0 >= bm0 + 256) return;

  const ushort* Ab = A + (long)blockIdx.z * sA;
  const ushort* Bb = Bt + (long)blockIdx.z * sB;

  int kEnd = K;
  if (KMODE == 1) { int ke = bm0 + 256; kEnd = ke < K ? ke : K; }
  const int nk = kEnd >> 5;          // K-tiles of 32

  // per buffer: A[256][32]bf16 = 16KB @ 0, B[128][32]bf16 = 8KB @ 16384
  __shared__ uint4 lds_v[73728 / 16];
  char* lds = (char*)lds_v;

  const int tid  = threadIdx.x;
  const int lane = tid & 63;
  const int wave = tid >> 6;
  const int wr   = wave >> 1;        // 0..3 -> rows wr*64
  const int wc   = wave & 1;         // 0..1 -> cols wc*64
  const int fr   = lane & 15;
  const int fg   = lane >> 4;        // 16B chunk (8 bf16 of k)

  f32x4 acc[4][4];
#pragma unroll
  for (int i = 0; i < 4; ++i)
#pragma unroll
    for (int j = 0; j < 4; ++j) acc[i][j] = (f32x4){0.f, 0.f, 0.f, 0.f};

  // stage tile tt into buf tt%3: A 2 segs/thread, B 1 seg/thread (3 loads)
  auto STAGE = [&](int tt) {
    if (tt >= nk) return;
    char* slab = lds + (tt % 3) * 24576;
#pragma unroll
    for (int u = 0; u < 2; ++u) {
      int s = u * 512 + tid;
      int row = s >> 2;                       // 0..255
      int cc = (s & 3) ^ ((row >> 1) & 3);    // pre-swizzled source chunk
      gload_lds16(Ab + (long)(bm0 + row) * K + tt * 32 + cc * 8,
                  (ushort*)(slab + s * 16));
    }
    {
      int s = tid;
      int row = s >> 2;                       // 0..127
      int cc = (s & 3) ^ ((row >> 1) & 3);
      gload_lds16(Bb + (long)(bn0 + row) * K + tt * 32 + cc * 8,
                  (ushort*)(slab + 16384 + s * 16));
    }
  };

  // prologue: stage t0, t1; wait for t0 (leave t1's 3 in flight)
  STAGE(0); STAGE(1);
  if (nk > 1) { WAITV3(); } else { WAITV0(); }
  SBAR();

  for (int t = 0; t < nk; ++t) {
    char* slab = lds + (t % 3) * 24576;
    STAGE(t + 2);                    // ~2 iterations of flight before needed

    short8 a[4], b[4];
#pragma unroll
    for (int i = 0; i < 4; ++i) {
      int row = wr * 64 + i * 16 + fr;
      int cc = fg ^ ((row >> 1) & 3);
      a[i] = *(const short8*)(slab + row * 64 + cc * 16);
    }
#pragma unroll
    for (int j = 0; j < 4; ++j) {
      int row = wc * 64 + j * 16 + fr;
      int cc = fg ^ ((row >> 1) & 3);
      b[j] = *(const short8*)(slab + 16384 + row * 64 + cc * 16);
    }
    WAITL0();
    __builtin_amdgcn_s_setprio(1);
#pragma unroll
    for (int i = 0; i < 4; ++i)
#pragma unroll
      for (int j = 0; j < 4; ++j)
        acc[i][j] = __builtin_amdgcn_mfma_f32_16x16x32_bf16(a[i], b[j], acc[i][j], 0, 0, 0);
    __builtin_amdgcn_s_setprio(0);

    // need t+1's 3 loads landed; t+2's 3 may stay in flight
    if (t + 2 < nk) { WAITV3(); } else { WAITV0(); }
    SBAR();
  }

  // epilogue: C/D map: col = lane&15, row = (lane>>4)*4 + r
  if (CMODE == 0) {
    ushort* Cb = (ushort*)C + (long)blockIdx.z * sC;
#pragma unroll
    for (int i = 0; i < 4; ++i)
#pragma unroll
      for (int j = 0; j < 4; ++j)
#pragma unroll
        for (int r = 0; r < 4; ++r) {
          int row = bm0 + wr * 64 + i * 16 + fg * 4 + r;
          int col = bn0 + wc * 64 + j * 16 + fr;
          Cb[(long)row * Nn + col] = f2bf(acc[i][j][r] * alpha);
        }
  } else {
    float* Cb = (float*)C + (long)blockIdx.z * sC;
#pragma unroll
    for (int i = 0; i < 4; ++i)
#pragma unroll
      for (int j = 0; j < 4; ++j)
#pragma unroll
        for (int r = 0; r < 4; ++r) {
          int row = bm0 + wr * 64 + i * 16 + fg * 4 + r;
          int col = bn0 + wc * 64 + j * 16 + fr;
          Cb[(long)row * Nn + col] = acc[i][j][r] * alpha;
        }
  }
}

// ---------------- 128^2 bf16 GEMM (PV with causal k-limit; high blocks/CU) ----------------
template <int CMODE, int KMODE>
__global__ __launch_bounds__(256) void gemm_bt(
    const ushort* __restrict__ A, const ushort* __restrict__ Bt, void* __restrict__ C,
    int M, int Nn, int K, long sA, long sB, long sC, float alpha)
{
  const int bm0 = blockIdx.x * BM;
  const int bn0 = blockIdx.y * BN;
  if (KMODE == 2 && bn0 > bm0) return;

  const ushort* Ab = A + (long)blockIdx.z * sA;
  const ushort* Bb = Bt + (long)blockIdx.z * sB;

  int kEnd = K;
  if (KMODE == 1) { int ke = bm0 + BM; kEnd = ke < K ? ke : K; }

  __shared__ ushort As[BM * BK];
  __shared__ ushort Bs[BN * BK];

  const int tid  = threadIdx.x;
  const int lane = tid & 63;
  const int wave = tid >> 6;
  const int wm   = (wave >> 1) * 64;
  const int wn   = (wave & 1) * 64;
  const int fr   = lane & 15;
  const int fg   = lane >> 4;

  f32x4 acc[4][4];
#pragma unroll
  for (int i = 0; i < 4; ++i)
#pragma unroll
    for (int j = 0; j < 4; ++j) acc[i][j] = (f32x4){0.f, 0.f, 0.f, 0.f};

  for (int k0 = 0; k0 < kEnd; k0 += BK) {
#pragma unroll
    for (int it = 0; it < 2; ++it) {
      int s = it * 256 + tid;
      int row = s >> 2;
      int col = (s & 3) * 8;
      gload_lds16(Ab + (long)(bm0 + row) * K + (k0 + col), &As[s * 8]);
      gload_lds16(Bb + (long)(bn0 + row) * K + (k0 + col), &Bs[s * 8]);
    }
    __syncthreads();

    short8 af[4], bfg[4];
#pragma unroll
    for (int i = 0; i < 4; ++i)
      af[i] = *(const short8*)&As[(wm + i * 16 + fr) * BK + fg * 8];
#pragma unroll
    for (int j = 0; j < 4; ++j)
      bfg[j] = *(const short8*)&Bs[(wn + j * 16 + fr) * BK + fg * 8];
#pragma unroll
    for (int i = 0; i < 4; ++i)
#pragma unroll
      for (int j = 0; j < 4; ++j)
        acc[i][j] = __builtin_amdgcn_mfma_f32_16x16x32_bf16(af[i], bfg[j], acc[i][j], 0, 0, 0);
    __syncthreads();
  }

  if (CMODE == 0) {
    ushort* Cb = (ushort*)C + (long)blockIdx.z * sC;
#pragma unroll
    for (int i = 0; i < 4; ++i)
#pragma unroll
      for (int j = 0; j < 4; ++j)
#pragma unroll
        for (int r = 0; r < 4; ++r) {
          int row = bm0 + wm + i * 16 + fg * 4 + r;
          int col = bn0 + wn + j * 16 + fr;
          Cb[(long)row * Nn + col] = f2bf(acc[i][j][r] * alpha);
        }
  } else {
    float* Cb = (float*)C + (long)blockIdx.z * sC;
#pragma unroll
    for (int i = 0; i < 4; ++i)
#pragma unroll
      for (int j = 0; j < 4; ++j)
#pragma unroll
        for (int r = 0; r < 4; ++r) {
          int row = bm0 + wm + i * 16 + fg * 4 + r;
          int col = bn0 + wn + j * 16 + fr;
          Cb[(long)row * Nn + col] = acc[i][j][r] * alpha;
        }
  }
}

// ---------------- bf16 transpose ----------------
__global__ void transpose_bf16(const ushort* __restrict__ in, ushort* __restrict__ out,
                               int rows, int cols) {
  __shared__ ushort t[64][65];
  int c0 = blockIdx.x * 64, r0 = blockIdx.y * 64;
  long base = (long)blockIdx.z * rows * cols;
  int tid = threadIdx.x;
#pragma unroll
  for (int i = 0; i < 16; ++i) {
    int idx = i * 256 + tid, r = idx >> 6, c = idx & 63;
    t[r][c] = in[base + (long)(r0 + r) * cols + c0 + c];
  }
  __syncthreads();
#pragma unroll
  for (int i = 0; i < 16; ++i) {
    int idx = i * 256 + tid, r = idx >> 6, c = idx & 63;
    out[base + (long)(c0 + r) * rows + r0 + c] = t[c][r];
  }
}

// ---------------- column softmax stats over q axis (8 cols/thread, 2-pass) ----------------
// grid (Nq/512, Nq/QCH, B), block 64 threads.  Partials: pM/pZ [b][NQC][Nq].
__global__ void colstats_partial(const ushort* __restrict__ S, float* __restrict__ pM,
                                 float* __restrict__ pZ, int Nq) {
  const int k0 = (blockIdx.x * 64 + threadIdx.x) * 8;
  const int qc = blockIdx.y;
  const int b  = blockIdx.z;
  const int q0 = qc * QCH, q1 = q0 + QCH;
  const long o = ((long)(b * NQC + qc)) * Nq + k0;

  float m[8], z[8];
#pragma unroll
  for (int j = 0; j < 8; ++j) { m[j] = -3.0e38f; z[j] = 0.f; }

  const int qs = q0 > k0 ? q0 : k0;          // causal: only q >= k valid
  if (qs < q1) {
    const ushort* Sb = S + (long)b * Nq * Nq;
    for (int q = qs; q < q1; ++q) {
      union { uint4 v; ushort u[8]; } d;
      d.v = *(const uint4*)(Sb + (long)q * Nq + k0);
#pragma unroll
      for (int j = 0; j < 8; ++j) {
        float s = bf2f(d.u[j]);
        m[j] = (q >= k0 + j) ? fmaxf(m[j], s) : m[j];
      }
    }
    for (int q = qs; q < q1; ++q) {
      union { uint4 v; ushort u[8]; } d;
      d.v = *(const uint4*)(Sb + (long)q * Nq + k0);
#pragma unroll
      for (int j = 0; j < 8; ++j) {
        float e = __expf(bf2f(d.u[j]) - m[j]);
        z[j] += (q >= k0 + j) ? e : 0.f;
      }
    }
  }
#pragma unroll
  for (int j = 0; j < 8; ++j) { pM[o + j] = m[j]; pZ[o + j] = z[j]; }
}

__global__ void colstats_combine(const float* __restrict__ pM, const float* __restrict__ pZ,
                                 float2* __restrict__ Mz, int Nq) {
  int idx = blockIdx.x * 256 + threadIdx.x;   // b*Nq + k
  int b = idx / Nq, k = idx - b * Nq;
  const float* PM = pM + (long)b * NQC * Nq + k;
  const float* PZ = pZ + (long)b * NQC * Nq + k;
  float M = -3.0e38f;
  for (int c = 0; c < NQC; ++c) M = fmaxf(M, PM[(long)c * Nq]);
  float Z = 0.f;
  for (int c = 0; c < NQC; ++c) Z += PZ[(long)c * Nq] * __expf(PM[(long)c * Nq] - M);
  Mz[idx] = make_float2(M, 1.0f / Z);
}

// ---------------- P = exp(s - M[k]) * rZ[k], over the PV READ SET, in place ------------
// PV (gemm_bt, q-tile [t*128,(t+1)*128)) reads k in [0, (t+1)*128): zero k>q up
// to the q-tile's 128 boundary; skip only groups beyond that.
__global__ void make_p(ushort* __restrict__ S, const float2* __restrict__ Mz, int Nq) {
  long t = (long)blockIdx.x * 256 + threadIdx.x;
  int kb = (int)(t % (Nq / 8)) * 8;
  long row = t / (Nq / 8);
  int q = (int)(row % Nq);
  int b = (int)(row / Nq);
  int kend = ((q >> 7) + 1) << 7;    // PV k-limit for this row's 128-tile
  if (kb >= kend) return;            // never read downstream
  ushort* Sp = S + row * Nq + kb;
  union { uint4 v; ushort u[8]; } d, o;
  d.v = *(const uint4*)Sp;
  const float2* mz = Mz + (long)b * Nq + kb;
#pragma unroll
  for (int j = 0; j < 8; ++j) {
    float2 m = mz[j];
    float p = (q >= kb + j) ? __expf(bf2f(d.u[j]) - m.x) * m.y : 0.f;
    o.u[j] = f2bf(p);
  }
  *(uint4*)Sp = o.v;
}

// ---------------- launch ----------------
extern "C" void kernel_launch(void* const* d_in, const int* in_sizes, int n_in,
                              void* d_out, int out_size, void* d_ws, size_t ws_size,
                              hipStream_t stream) {
  const float* x  = (const float*)d_in[0];
  const float* Wq = (const float*)d_in[1];
  const float* Wk = (const float*)d_in[2];
  const float* Wv = (const float*)d_in[3];
  float* out = (float*)d_out;

  const int B = 4, N = 2048, D = 1024;
  const long BND = (long)B * N * D;

  char* ws = (char*)d_ws;
  ushort* xb  = (ushort*)ws;                         // [B*N][D] bf16, 16MB
  ushort* Vt  = xb;                                  // aliases xb (dead after K1)
  ushort* Wb  = xb + BND;                            // [3][D][D] bf16
  ushort* QKV = Wb + 3L * D * D;                     // [3][B*N][D]
  ushort* Qb  = QKV;
  ushort* Kb  = QKV + BND;
  ushort* Vb  = QKV + 2 * BND;
  ushort* S   = QKV + 3 * BND;                       // [B][N][N] bf16
  float*  pM  = (float*)(S + (long)B * N * N);       // [B][NQC][N] f32, 2MB
  float*  pZ  = pM + (long)B * NQC * N;              // 2MB
  float2* Mz  = (float2*)(pZ + (long)B * NQC * N);   // [B][N]

  // K0: all casts in one dispatch
  {
    int n_x4 = (int)(BND / 4);          // 2097152
    int n_w4 = D * D / 4;               // 262144
    int total = n_x4 + 3 * n_w4;        // 2883584
    cast_all<<<total / 256, 256, 0, stream>>>(x, Wq, Wk, Wv, xb, Wb, n_x4, n_w4);
  }

  // K1: Q/K/V projections: 768 blocks = exactly 3/CU at 2 blocks/CU resident
  {
    dim3 g(B * N / 256, D / 128, 3);
    gemm256c<0, 0><<<g, 512, 0, stream>>>(xb, Wb, (void*)QKV, B * N, D, D,
                                          0L, (long)D * D, BND, 1.0f);
  }

  // K2: V -> V^T (xb dead now)
  {
    dim3 g(D / 64, N / 64, B);
    transpose_bf16<<<g, 256, 0, stream>>>(Vb, Vt, N, D);
  }

  // K3: S = Q K^T / 32, tiles with bn0 < bm0+256 only (288 live blocks)
  {
    dim3 g(N / 256, N / 128, B);
    gemm256c<0, 2><<<g, 512, 0, stream>>>(Qb, Kb, (void*)S, N, N, D,
                                          (long)N * D, (long)N * D, (long)N * N, 0.03125f);
  }

  // K3b: column (query-axis) softmax stats
  {
    dim3 g(N / 512, N / QCH, B);
    colstats_partial<<<g, 64, 0, stream>>>(S, pM, pZ, N);
    colstats_combine<<<(B * N) / 256, 256, 0, stream>>>(pM, pZ, Mz, N);
  }

  // K4: P in place (PV read set, 128-tile boundary)
  make_p<<<(int)((long)B * N * N / 8 / 256), 256, 0, stream>>>(S, Mz, N);

  // K5: O = P @ V (kEnd = bm0+128), 512 triangular blocks, high occupancy
  {
    dim3 g(N / BM, D / BN, B);
    gemm_bt<1, 1><<<g, 256, 0, stream>>>(S, Vt, (void*)out, N, D, N,
                                         (long)N * N, (long)D * N, (long)N * D, 1.0f);
  }
}

// Round 8
// 218.658 us; speedup vs baseline: 1.1346x; 1.0969x over previous
//
#include <hip/hip_runtime.h>
#include <stdint.h>

// CausalSelfAttention, B=4 N=2048 D=1024, softmax over QUERY axis (axis=1).
// Pipeline: cast(1 kernel) | QKV gemm (256x128 BK=32 triple-buf vmcnt(3)) |
//           V transpose | S=QK^T/32 (same kernel, causal skip, bf16) |
//           column stats (ILP 8-col/thread) | P=exp(s-M)*rZ (PV-read set) |
//           O = P @ V (gemm_pv: paired q-tiles (tq,15-tq), balanced 1 block/CU).

#define QCH 32
#define NQC 64   // N / QCH

typedef __attribute__((ext_vector_type(8))) short short8;   // 8 bf16 = 4 VGPR
typedef __attribute__((ext_vector_type(4))) float f32x4;

static __device__ __forceinline__ ushort f2bf(float f) {
  union { float f; uint32_t u; } v; v.f = f;
  uint32_t r = v.u + 0x7FFFu + ((v.u >> 16) & 1u);   // RNE
  return (ushort)(r >> 16);
}
static __device__ __forceinline__ float bf2f(ushort u) {
  union { uint32_t u; float f; } v; v.u = ((uint32_t)u) << 16;
  return v.f;
}

static __device__ __forceinline__ void gload_lds16(const ushort* g, ushort* l) {
  __builtin_amdgcn_global_load_lds(
      (const __attribute__((address_space(1))) void*)g,
      (__attribute__((address_space(3))) void*)l, 16, 0, 0);
}

#define SBAR()   __builtin_amdgcn_s_barrier()
#define SCHED0() __builtin_amdgcn_sched_barrier(0)
#define WAITL0() do { asm volatile("s_waitcnt lgkmcnt(0)" ::: "memory"); SCHED0(); } while (0)
#define WAITV3() asm volatile("s_waitcnt vmcnt(3)" ::: "memory")
#define WAITV2() asm volatile("s_waitcnt vmcnt(2)" ::: "memory")
#define WAITV0() asm volatile("s_waitcnt vmcnt(0)" ::: "memory")

// ---------------- merged casts (x + Wq + Wk + Wv in one dispatch) ----------------
__global__ void cast_all(const float* __restrict__ x, const float* __restrict__ Wq,
                         const float* __restrict__ Wk, const float* __restrict__ Wv,
                         ushort* __restrict__ xb, ushort* __restrict__ Wb,
                         int n_x4, int n_w4) {
  int i = blockIdx.x * blockDim.x + threadIdx.x;
  const float* src; ushort* dst; int off;
  if (i < n_x4) { src = x; dst = xb; off = i; }
  else {
    int j = i - n_x4;
    int z = j / n_w4;
    off = j - z * n_w4;
    src = (z == 0) ? Wq : (z == 1) ? Wk : Wv;
    dst = Wb + (long)z * n_w4 * 4;
  }
  float4 v = ((const float4*)src)[off];
  ushort4 o;
  o.x = f2bf(v.x); o.y = f2bf(v.y); o.z = f2bf(v.z); o.w = f2bf(v.w);
  ((ushort4*)dst)[off] = o;
}

// =====================================================================
// 256(M) x 128(N) / BK=32 / 8-wave / TRIPLE-buffer LDS (3 x 24KB = 72KB)
// 2 blocks/CU; STAGE(t+2), counted vmcnt(3).  C = alpha * A @ Bt^T.
// CMODE: 0 = bf16 C, 1 = f32 C.
// KMODE: 0 = full K; 2 = skip blocks with bn0 >= bm0+256 (causal S).
// Swizzle (verified 0 conflicts): chunk c of row stored at c ^ ((row>>1)&3).
// =====================================================================
template <int CMODE, int KMODE>
__global__ __launch_bounds__(512, 4) void gemm256c(
    const ushort* __restrict__ A, const ushort* __restrict__ Bt, void* __restrict__ C,
    int M, int Nn, int K, long sA, long sB, long sC, float alpha)
{
  const int bm0 = blockIdx.x * 256;
  const int bn0 = blockIdx.y * 128;
  if (KMODE == 2 && bn0 >= bm0 + 256) return;

  const ushort* Ab = A + (long)blockIdx.z * sA;
  const ushort* Bb = Bt + (long)blockIdx.z * sB;

  const int nk = K >> 5;             // K-tiles of 32

  __shared__ uint4 lds_v[73728 / 16];
  char* lds = (char*)lds_v;

  const int tid  = threadIdx.x;
  const int lane = tid & 63;
  const int wave = tid >> 6;
  const int wr   = wave >> 1;        // 0..3 -> rows wr*64
  const int wc   = wave & 1;         // 0..1 -> cols wc*64
  const int fr   = lane & 15;
  const int fg   = lane >> 4;

  f32x4 acc[4][4];
#pragma unroll
  for (int i = 0; i < 4; ++i)
#pragma unroll
    for (int j = 0; j < 4; ++j) acc[i][j] = (f32x4){0.f, 0.f, 0.f, 0.f};

  auto STAGE = [&](int tt) {
    if (tt >= nk) return;
    char* slab = lds + (tt % 3) * 24576;
#pragma unroll
    for (int u = 0; u < 2; ++u) {
      int s = u * 512 + tid;
      int row = s >> 2;
      int cc = (s & 3) ^ ((row >> 1) & 3);
      gload_lds16(Ab + (long)(bm0 + row) * K + tt * 32 + cc * 8,
                  (ushort*)(slab + s * 16));
    }
    {
      int s = tid;
      int row = s >> 2;
      int cc = (s & 3) ^ ((row >> 1) & 3);
      gload_lds16(Bb + (long)(bn0 + row) * K + tt * 32 + cc * 8,
                  (ushort*)(slab + 16384 + s * 16));
    }
  };

  STAGE(0); STAGE(1);
  if (nk > 1) { WAITV3(); } else { WAITV0(); }
  SBAR();

  for (int t = 0; t < nk; ++t) {
    char* slab = lds + (t % 3) * 24576;
    STAGE(t + 2);

    short8 a[4], b[4];
#pragma unroll
    for (int i = 0; i < 4; ++i) {
      int row = wr * 64 + i * 16 + fr;
      int cc = fg ^ ((row >> 1) & 3);
      a[i] = *(const short8*)(slab + row * 64 + cc * 16);
    }
#pragma unroll
    for (int j = 0; j < 4; ++j) {
      int row = wc * 64 + j * 16 + fr;
      int cc = fg ^ ((row >> 1) & 3);
      b[j] = *(const short8*)(slab + 16384 + row * 64 + cc * 16);
    }
    WAITL0();
    __builtin_amdgcn_s_setprio(1);
#pragma unroll
    for (int i = 0; i < 4; ++i)
#pragma unroll
      for (int j = 0; j < 4; ++j)
        acc[i][j] = __builtin_amdgcn_mfma_f32_16x16x32_bf16(a[i], b[j], acc[i][j], 0, 0, 0);
    __builtin_amdgcn_s_setprio(0);

    if (t + 2 < nk) { WAITV3(); } else { WAITV0(); }
    SBAR();
  }

  if (CMODE == 0) {
    ushort* Cb = (ushort*)C + (long)blockIdx.z * sC;
#pragma unroll
    for (int i = 0; i < 4; ++i)
#pragma unroll
      for (int j = 0; j < 4; ++j)
#pragma unroll
        for (int r = 0; r < 4; ++r) {
          int row = bm0 + wr * 64 + i * 16 + fg * 4 + r;
          int col = bn0 + wc * 64 + j * 16 + fr;
          Cb[(long)row * Nn + col] = f2bf(acc[i][j][r] * alpha);
        }
  } else {
    float* Cb = (float*)C + (long)blockIdx.z * sC;
#pragma unroll
    for (int i = 0; i < 4; ++i)
#pragma unroll
      for (int j = 0; j < 4; ++j)
#pragma unroll
        for (int r = 0; r < 4; ++r) {
          int row = bm0 + wr * 64 + i * 16 + fg * 4 + r;
          int col = bn0 + wc * 64 + j * 16 + fr;
          Cb[(long)row * Nn + col] = acc[i][j][r] * alpha;
        }
  }
}

// =====================================================================
// PV GEMM, statically balanced: 256 blocks (1/CU), each computes TWO
// 128x128 tiles for q-tiles (tq, 15-tq); kEnd sum = 17*128 constant.
// 512 thr / 8 waves, wave-tile 64x32 (wr=wave>>2, wc=wave&3), acc 4x2.
// Triple-buffer 3x16KB, STAGE(t+2), counted vmcnt(2), swizzled (0-conflict).
// A = P [B][N][N] bf16; Bt = Vt [B][D][N] bf16; out [B][N][D] f32.
// =====================================================================
__global__ __launch_bounds__(512, 2) void gemm_pv(
    const ushort* __restrict__ P, const ushort* __restrict__ Vt, float* __restrict__ out)
{
  const int NQ = 2048, DD = 1024;
  const int L = blockIdx.x;
  const int pr = L & 7, dt = (L >> 3) & 7, b = L >> 6;

  const ushort* Pb = P + (long)b * NQ * NQ;
  const ushort* Vb = Vt + (long)b * DD * NQ + (long)(dt * 128) * NQ;  // 128 d-rows
  float* Ob = out + (long)b * NQ * DD;

  __shared__ uint4 lds_v[49152 / 16];
  char* lds = (char*)lds_v;

  const int tid  = threadIdx.x;
  const int lane = tid & 63;
  const int wave = tid >> 6;
  const int wr   = wave >> 2;        // 0..1 -> 64-row half
  const int wc   = wave & 3;         // 0..3 -> 32-col quarter
  const int fr   = lane & 15;
  const int fg   = lane >> 4;

  for (int h = 0; h < 2; ++h) {
    const int tq = h ? (15 - pr) : pr;
    const int q0 = tq * 128;
    const ushort* Aq = Pb + (long)q0 * NQ;
    const int nk = (tq + 1) * 4;     // K-steps of 32; kEnd=(tq+1)*128

    f32x4 acc[4][2];
#pragma unroll
    for (int i = 0; i < 4; ++i)
#pragma unroll
      for (int j = 0; j < 2; ++j) acc[i][j] = (f32x4){0.f, 0.f, 0.f, 0.f};

    // per buffer: A[128][32] 8KB @0, B[128][32] 8KB @8192; 2 loads/thread
    auto STAGE = [&](int tt) {
      if (tt >= nk) return;
      char* slab = lds + (tt % 3) * 16384;
      {
        int s = tid;
        int row = s >> 2;                       // 0..127
        int cc = (s & 3) ^ ((row >> 1) & 3);
        gload_lds16(Aq + (long)row * NQ + tt * 32 + cc * 8,
                    (ushort*)(slab + s * 16));
      }
      {
        int s = tid;
        int row = s >> 2;
        int cc = (s & 3) ^ ((row >> 1) & 3);
        gload_lds16(Vb + (long)row * NQ + tt * 32 + cc * 8,
                    (ushort*)(slab + 8192 + s * 16));
      }
    };

    STAGE(0); STAGE(1);
    WAITV2();
    SBAR();

    for (int t = 0; t < nk; ++t) {
      char* slab = lds + (t % 3) * 16384;
      STAGE(t + 2);

      short8 a[4], bfr[2];
#pragma unroll
      for (int i = 0; i < 4; ++i) {
        int row = wr * 64 + i * 16 + fr;
        int cc = fg ^ ((row >> 1) & 3);
        a[i] = *(const short8*)(slab + row * 64 + cc * 16);
      }
#pragma unroll
      for (int j = 0; j < 2; ++j) {
        int row = wc * 32 + j * 16 + fr;
        int cc = fg ^ ((row >> 1) & 3);
        bfr[j] = *(const short8*)(slab + 8192 + row * 64 + cc * 16);
      }
      WAITL0();
      __builtin_amdgcn_s_setprio(1);
#pragma unroll
      for (int i = 0; i < 4; ++i)
#pragma unroll
        for (int j = 0; j < 2; ++j)
          acc[i][j] = __builtin_amdgcn_mfma_f32_16x16x32_bf16(a[i], bfr[j], acc[i][j], 0, 0, 0);
      __builtin_amdgcn_s_setprio(0);

      if (t + 2 < nk) { WAITV2(); } else { WAITV0(); }
      SBAR();
    }

    // epilogue: col = lane&15, row = (lane>>4)*4 + r
#pragma unroll
    for (int i = 0; i < 4; ++i)
#pragma unroll
      for (int j = 0; j < 2; ++j)
#pragma unroll
        for (int r = 0; r < 4; ++r) {
          int row = q0 + wr * 64 + i * 16 + fg * 4 + r;
          int col = dt * 128 + wc * 32 + j * 16 + fr;
          Ob[(long)row * DD + col] = acc[i][j][r];
        }
  }
}

// ---------------- bf16 transpose ----------------
__global__ void transpose_bf16(const ushort* __restrict__ in, ushort* __restrict__ out,
                               int rows, int cols) {
  __shared__ ushort t[64][65];
  int c0 = blockIdx.x * 64, r0 = blockIdx.y * 64;
  long base = (long)blockIdx.z * rows * cols;
  int tid = threadIdx.x;
#pragma unroll
  for (int i = 0; i < 16; ++i) {
    int idx = i * 256 + tid, r = idx >> 6, c = idx & 63;
    t[r][c] = in[base + (long)(r0 + r) * cols + c0 + c];
  }
  __syncthreads();
#pragma unroll
  for (int i = 0; i < 16; ++i) {
    int idx = i * 256 + tid, r = idx >> 6, c = idx & 63;
    out[base + (long)(c0 + r) * rows + r0 + c] = t[c][r];
  }
}

// ---------------- column softmax stats over q axis (8 cols/thread, 2-pass) ----------------
__global__ void colstats_partial(const ushort* __restrict__ S, float* __restrict__ pM,
                                 float* __restrict__ pZ, int Nq) {
  const int k0 = (blockIdx.x * 64 + threadIdx.x) * 8;
  const int qc = blockIdx.y;
  const int b  = blockIdx.z;
  const int q0 = qc * QCH, q1 = q0 + QCH;
  const long o = ((long)(b * NQC + qc)) * Nq + k0;

  float m[8], z[8];
#pragma unroll
  for (int j = 0; j < 8; ++j) { m[j] = -3.0e38f; z[j] = 0.f; }

  const int qs = q0 > k0 ? q0 : k0;          // causal: only q >= k valid
  if (qs < q1) {
    const ushort* Sb = S + (long)b * Nq * Nq;
    for (int q = qs; q < q1; ++q) {
      union { uint4 v; ushort u[8]; } d;
      d.v = *(const uint4*)(Sb + (long)q * Nq + k0);
#pragma unroll
      for (int j = 0; j < 8; ++j) {
        float s = bf2f(d.u[j]);
        m[j] = (q >= k0 + j) ? fmaxf(m[j], s) : m[j];
      }
    }
    for (int q = qs; q < q1; ++q) {
      union { uint4 v; ushort u[8]; } d;
      d.v = *(const uint4*)(Sb + (long)q * Nq + k0);
#pragma unroll
      for (int j = 0; j < 8; ++j) {
        float e = __expf(bf2f(d.u[j]) - m[j]);
        z[j] += (q >= k0 + j) ? e : 0.f;
      }
    }
  }
#pragma unroll
  for (int j = 0; j < 8; ++j) { pM[o + j] = m[j]; pZ[o + j] = z[j]; }
}

__global__ void colstats_combine(const float* __restrict__ pM, const float* __restrict__ pZ,
                                 float2* __restrict__ Mz, int Nq) {
  int idx = blockIdx.x * 256 + threadIdx.x;   // b*Nq + k
  int b = idx / Nq, k = idx - b * Nq;
  const float* PM = pM + (long)b * NQC * Nq + k;
  const float* PZ = pZ + (long)b * NQC * Nq + k;
  float M = -3.0e38f;
  for (int c = 0; c < NQC; ++c) M = fmaxf(M, PM[(long)c * Nq]);
  float Z = 0.f;
  for (int c = 0; c < NQC; ++c) Z += PZ[(long)c * Nq] * __expf(PM[(long)c * Nq] - M);
  Mz[idx] = make_float2(M, 1.0f / Z);
}

// ---------------- P = exp(s - M[k]) * rZ[k], over the PV READ SET, in place ------------
// PV (q-tile [t*128,(t+1)*128)) reads k in [0, (t+1)*128): zero k>q up to the
// q-tile's 128 boundary; skip only groups beyond that.
__global__ void make_p(ushort* __restrict__ S, const float2* __restrict__ Mz, int Nq) {
  long t = (long)blockIdx.x * 256 + threadIdx.x;
  int kb = (int)(t % (Nq / 8)) * 8;
  long row = t / (Nq / 8);
  int q = (int)(row % Nq);
  int b = (int)(row / Nq);
  int kend = ((q >> 7) + 1) << 7;    // PV k-limit for this row's 128-tile
  if (kb >= kend) return;            // never read downstream
  ushort* Sp = S + row * Nq + kb;
  union { uint4 v; ushort u[8]; } d, o;
  d.v = *(const uint4*)Sp;
  const float2* mz = Mz + (long)b * Nq + kb;
#pragma unroll
  for (int j = 0; j < 8; ++j) {
    float2 m = mz[j];
    float p = (q >= kb + j) ? __expf(bf2f(d.u[j]) - m.x) * m.y : 0.f;
    o.u[j] = f2bf(p);
  }
  *(uint4*)Sp = o.v;
}

// ---------------- launch ----------------
extern "C" void kernel_launch(void* const* d_in, const int* in_sizes, int n_in,
                              void* d_out, int out_size, void* d_ws, size_t ws_size,
                              hipStream_t stream) {
  const float* x  = (const float*)d_in[0];
  const float* Wq = (const float*)d_in[1];
  const float* Wk = (const float*)d_in[2];
  const float* Wv = (const float*)d_in[3];
  float* out = (float*)d_out;

  const int B = 4, N = 2048, D = 1024;
  const long BND = (long)B * N * D;

  char* ws = (char*)d_ws;
  ushort* xb  = (ushort*)ws;                         // [B*N][D] bf16, 16MB
  ushort* Vt  = xb;                                  // aliases xb (dead after K1)
  ushort* Wb  = xb + BND;                            // [3][D][D] bf16
  ushort* QKV = Wb + 3L * D * D;                     // [3][B*N][D]
  ushort* Qb  = QKV;
  ushort* Kb  = QKV + BND;
  ushort* Vb  = QKV + 2 * BND;
  ushort* S   = QKV + 3 * BND;                       // [B][N][N] bf16
  float*  pM  = (float*)(S + (long)B * N * N);       // [B][NQC][N] f32, 2MB
  float*  pZ  = pM + (long)B * NQC * N;              // 2MB
  float2* Mz  = (float2*)(pZ + (long)B * NQC * N);   // [B][N]

  // K0: all casts in one dispatch
  {
    int n_x4 = (int)(BND / 4);          // 2097152
    int n_w4 = D * D / 4;               // 262144
    int total = n_x4 + 3 * n_w4;        // 2883584
    cast_all<<<total / 256, 256, 0, stream>>>(x, Wq, Wk, Wv, xb, Wb, n_x4, n_w4);
  }

  // K1: Q/K/V projections: 768 blocks = exactly 3/CU at 2 blocks/CU resident
  {
    dim3 g(B * N / 256, D / 128, 3);
    gemm256c<0, 0><<<g, 512, 0, stream>>>(xb, Wb, (void*)QKV, B * N, D, D,
                                          0L, (long)D * D, BND, 1.0f);
  }

  // K2: V -> V^T (xb dead now)
  {
    dim3 g(D / 64, N / 64, B);
    transpose_bf16<<<g, 256, 0, stream>>>(Vb, Vt, N, D);
  }

  // K3: S = Q K^T / 32, tiles with bn0 < bm0+256 only (288 live blocks)
  {
    dim3 g(N / 256, N / 128, B);
    gemm256c<0, 2><<<g, 512, 0, stream>>>(Qb, Kb, (void*)S, N, N, D,
                                          (long)N * D, (long)N * D, (long)N * N, 0.03125f);
  }

  // K3b: column (query-axis) softmax stats
  {
    dim3 g(N / 512, N / QCH, B);
    colstats_partial<<<g, 64, 0, stream>>>(S, pM, pZ, N);
    colstats_combine<<<(B * N) / 256, 256, 0, stream>>>(pM, pZ, Mz, N);
  }

  // K4: P in place (PV read set, 128-tile boundary)
  make_p<<<(int)((long)B * N * N / 8 / 256), 256, 0, stream>>>(S, Mz, N);

  // K5: O = P @ V — balanced paired q-tiles, 256 blocks = 1/CU
  gemm_pv<<<256, 512, 0, stream>>>(S, Vt, out);
}